// Round 7
// baseline (3420.641 us; speedup 1.0000x reference)
//
#include <hip/hip_runtime.h>

typedef _Float16 f16;
typedef _Float16 h8 __attribute__((ext_vector_type(8)));
typedef float f32x4 __attribute__((ext_vector_type(4)));

#define MFMA16(a,b,c) __builtin_amdgcn_mfma_f32_16x16x32_f16((a),(b),(c),0,0,0)
#define MFMA8(a,b,c)  __builtin_amdgcn_mfma_f32_16x16x32_fp8_bf8((long)(a),(long)(b),(c),0,0,0)

#define TT 256
#define BB 4096
#define OUTD 8

// ---- workspace offsets (bytes), identical to round 2 ----
#define WS_WHH    0u         // [768][256] f16 * 2^8   (gate order r,z,n)
#define WS_WIHHI  393216u    // [768][32]  f16 * 2^8
#define WS_WIHLO  442368u    // [768][32]  e5m2 residual * 2^8
#define WS_WLON   466944u    // [256][256] e5m2 n-gate Whh residual * 2^8 (L2-streamed)
#define WS_WLAT   532480u    // [32][256]  f16
#define WS_W1T    548864u    // [512][32]  f16
#define WS_W2T    581632u    // [512][512] f16
#define WS_W3T    1105920u   // [32][512]  f16
#define WS_WD1T   1138688u   // [256][32]  f16
#define WS_WD2T   1155072u   // [16][256]  f16 (rows>=8 zero)

// ---- LDS offsets (bytes): R2 layout with WLN region repurposed as WRT ----
#define L_HB     0           // [16][1024]: hi [0,512) | lo [512,1024), swz ^((row&7)<<4)
#define L_WIHHI  16384       // [768][64B] f16, swz ^((n&3)<<4)
#define L_WIHLO  65536       // [768][32B] fp8, swz ^((n&3)<<3)
#define L_WRT    90112       // r-gate tiles 0,1: [128 rows][512B] f16, swz ^((row&7)<<4)
                             //   row = wave*32 + t*16 + lr  <->  col c = wave*64 + t*16 + lr
#define L_CST    155648      // [256][7] f32
#define LDS_SIZE 162816

__device__ __forceinline__ float fsigm(float x) {
  return __builtin_amdgcn_rcpf(1.f + __builtin_amdgcn_exp2f(-1.44269504f * x));
}
__device__ __forceinline__ float ftanh(float x) {
  return 1.f - 2.f * __builtin_amdgcn_rcpf(1.f + __builtin_amdgcn_exp2f(2.88539008f * x));
}
__device__ __forceinline__ f32x4 splat4(float v) { f32x4 r = {v, v, v, v}; return r; }

__device__ __forceinline__ long long pack_e4m3_h8(h8 a) {
  int lo = __builtin_amdgcn_cvt_pk_fp8_f32((float)a[0], (float)a[1], 0, false);
  lo = __builtin_amdgcn_cvt_pk_fp8_f32((float)a[2], (float)a[3], lo, true);
  int hi = __builtin_amdgcn_cvt_pk_fp8_f32((float)a[4], (float)a[5], 0, false);
  hi = __builtin_amdgcn_cvt_pk_fp8_f32((float)a[6], (float)a[7], hi, true);
  return (long long)(unsigned)lo | ((long long)hi << 32);
}
__device__ __forceinline__ long long pack_e4m3_f32x8(f32x4 a, f32x4 b) {
  int lo = __builtin_amdgcn_cvt_pk_fp8_f32(a[0], a[1], 0, false);
  lo = __builtin_amdgcn_cvt_pk_fp8_f32(a[2], a[3], lo, true);
  int hi = __builtin_amdgcn_cvt_pk_fp8_f32(b[0], b[1], 0, false);
  hi = __builtin_amdgcn_cvt_pk_fp8_f32(b[2], b[3], hi, true);
  return (long long)(unsigned)lo | ((long long)hi << 32);
}

// ---------------- prep: unchanged from round 2 (validated) ----------------
__global__ __launch_bounds__(512) void prep_kernel(
    const float* __restrict__ Wih, const float* __restrict__ Whh,
    const float* __restrict__ Wlat, const float* __restrict__ W1,
    const float* __restrict__ W2, const float* __restrict__ W3,
    const float* __restrict__ Wd1, const float* __restrict__ Wd2,
    char* __restrict__ ws) {
  int idx = blockIdx.x * 512 + threadIdx.x;
  if (idx < 768*256) {
    int n = idx >> 8, k = idx & 255;
    ((f16*)(ws + WS_WHH))[n*256 + k] = (f16)(Whh[k*768 + n] * 256.f);
  }
  if (idx < 768*32) {
    int n = idx >> 5, k = idx & 31;
    ((f16*)(ws + WS_WIHHI))[n*32 + k] = (f16)(Wih[k*768 + n] * 256.f);
  }
  if (idx < 768*16) {
    int n = idx >> 4, k2 = (idx & 15) * 2;
    float w0 = Wih[k2*768 + n] * 256.f;
    float w1 = Wih[(k2+1)*768 + n] * 256.f;
    float r0 = w0 - (float)(f16)w0;
    float r1 = w1 - (float)(f16)w1;
    int p = __builtin_amdgcn_cvt_pk_bf8_f32(r0, r1, 0, false);
    *(short*)(ws + WS_WIHLO + n*32 + k2) = (short)p;
  }
  if (idx < 256*128) {
    int n = idx >> 7, k2 = (idx & 127) * 2;
    int c = 512 + n;
    float w0 = Whh[k2*768 + c] * 256.f;
    float w1 = Whh[(k2+1)*768 + c] * 256.f;
    float r0 = w0 - (float)(f16)w0;
    float r1 = w1 - (float)(f16)w1;
    int p = __builtin_amdgcn_cvt_pk_bf8_f32(r0, r1, 0, false);
    *(short*)(ws + WS_WLON + n*256 + k2) = (short)p;
  }
  if (idx < 32*256)  { int n = idx >> 8, k = idx & 255; ((f16*)(ws + WS_WLAT))[n*256 + k] = (f16)Wlat[k*64 + n]; }
  if (idx < 512*32)  { int n = idx >> 5, k = idx & 31;  ((f16*)(ws + WS_W1T))[n*32 + k]   = (f16)W1[k*512 + n]; }
  if (idx < 512*512) { int n = idx >> 9, k = idx & 511; ((f16*)(ws + WS_W2T))[n*512 + k]  = (f16)W2[k*512 + n]; }
  if (idx < 32*512)  { int n = idx >> 9, k = idx & 511; ((f16*)(ws + WS_W3T))[n*512 + k]  = (f16)W3[k*32 + n]; }
  if (idx < 256*32)  { int n = idx >> 5, k = idx & 31;  ((f16*)(ws + WS_WD1T))[n*32 + k]  = (f16)Wd1[k*256 + n]; }
  if (idx < 16*256)  { int n = idx >> 8, k = idx & 255; ((f16*)(ws + WS_WD2T))[n*256 + k] = (n < 8) ? (f16)Wd2[k*8 + n] : (f16)0.f; }
}

// ---------------- main: 256 blocks x 256 threads (4 waves), 16 batch rows/block ----------------
// R2 body verbatim except: (a) r-gate tiles 0,1 read from LDS (WRT) instead of regs,
// (b) WLN fp8 streamed from global/L2, (c) amdgpu_waves_per_eu(1,1) so the allocator
// uses the full 512-reg budget (LDS caps occupancy at 1 block/CU anyway).
__global__ __launch_bounds__(256, 1) __attribute__((amdgpu_waves_per_eu(1, 1)))
void gru_ode_kernel(
    const float* __restrict__ xh, const float* __restrict__ th,
    const float* __restrict__ Wih_f, const float* __restrict__ bih,
    const float* __restrict__ bhh, const float* __restrict__ blat,
    const float* __restrict__ b1, const float* __restrict__ b2,
    const float* __restrict__ b3, const float* __restrict__ bd1,
    const float* __restrict__ bd2, const char* __restrict__ ws,
    float* __restrict__ out) {
  extern __shared__ char smem[];
  char* HB  = smem + L_HB;
  char* WIH = smem + L_WIHHI;
  char* WIL = smem + L_WIHLO;
  char* WRT = smem + L_WRT;
  float* CST = (float*)(smem + L_CST);
  const char* wlng = ws + WS_WLON;

  const int tid  = threadIdx.x;
  const int wave = tid >> 6;
  const int lane = tid & 63;
  const int lq   = lane >> 4;
  const int lr   = lane & 15;
  const int m0   = blockIdx.x << 4;
  const int swz  = (lr & 7) << 4;
  const float S  = 1.f / 256.f;

  // ---- stage LDS (R2 code; + WRT staging) ----
  #pragma unroll
  for (int it = 0; it < 16; ++it) ((unsigned*)HB)[tid + it*256] = 0u;
  {
    const unsigned* src = (const unsigned*)(ws + WS_WIHHI);
    #pragma unroll
    for (int it = 0; it < 48; ++it) {
      int i = tid + it*256; int n = i >> 4, kw = i & 15;
      *(unsigned*)(WIH + n*64 + ((kw*4) ^ ((n & 3) << 4))) = src[i];
    }
  }
  {
    const unsigned* src = (const unsigned*)(ws + WS_WIHLO);
    #pragma unroll
    for (int it = 0; it < 24; ++it) {
      int i = tid + it*256; int n = i >> 3, kw = i & 7;
      *(unsigned*)(WIL + n*32 + ((kw*4) ^ ((n & 3) << 3))) = src[i];
    }
  }
  {
    // r-gate tiles 0,1: col c = wave*64 + t*16 + lr -> LDS row = wave*32 + t*16 + lr
    #pragma unroll
    for (int it = 0; it < 64; ++it) {
      int i = tid + it*256;             // dword index, 16384 total
      int row = i >> 7, kw = i & 127;
      int c = ((row >> 5) << 6) + (row & 31);
      unsigned v = *(const unsigned*)(ws + WS_WHH + c*512 + kw*4);
      *(unsigned*)(WRT + row*512 + ((kw*4) ^ ((row & 7) << 4))) = v;
    }
  }
  if (tid < 256) {
    int c = tid;
    CST[c*7 + 0] = Wih_f[32*768 + c];
    CST[c*7 + 1] = Wih_f[32*768 + 256 + c];
    CST[c*7 + 2] = Wih_f[32*768 + 512 + c];
    CST[c*7 + 3] = bih[c] + bhh[c];
    CST[c*7 + 4] = bih[256 + c] + bhh[256 + c];
    CST[c*7 + 5] = bih[512 + c];
    CST[c*7 + 6] = bhh[512 + c];
  }

  // ---- resident weights (R2 addresses): z,n all 4 tiles; r tiles 2,3 only ----
  h8 Wfz[4][8], Wfn[4][8], Wfr[2][8];
  #pragma unroll
  for (int t = 0; t < 4; ++t) {
    const char* bz = ws + WS_WHH + (256 + wave*64 + t*16 + lr)*512 + lq*16;
    const char* bn = ws + WS_WHH + (512 + wave*64 + t*16 + lr)*512 + lq*16;
    #pragma unroll
    for (int kc = 0; kc < 8; ++kc) {
      Wfz[t][kc] = *(const h8*)(bz + kc*64);
      Wfn[t][kc] = *(const h8*)(bn + kc*64);
    }
  }
  #pragma unroll
  for (int t = 0; t < 2; ++t) {
    const char* br = ws + WS_WHH + (wave*64 + (t + 2)*16 + lr)*512 + lq*16;
    #pragma unroll
    for (int kc = 0; kc < 8; ++kc) Wfr[t][kc] = *(const h8*)(br + kc*64);
  }

  float hreg[4][4];
  #pragma unroll
  for (int t = 0; t < 4; ++t)
    #pragma unroll
    for (int r = 0; r < 4; ++r) hreg[t][r] = 0.f;

  const int wrt0 = (wave*32 + lr)*512;   // t=0 row; t=1 at +8192

  __syncthreads();

  // ---- GRU loop (reversed sequence), R2 protocol: in-place HB, 2 barriers/step ----
  #pragma unroll 1
  for (int s = 0; s < 256; ++s) {
    const int tsrc = 255 - s;
    // global prefetches (latency hidden under h-part MFMAs)
    f32x4 xa = *(const f32x4*)(xh + (size_t)(tsrc*BB + m0 + lr)*32 + lq*8);
    f32x4 xb = *(const f32x4*)(xh + (size_t)(tsrc*BB + m0 + lr)*32 + lq*8 + 4);
    f32x4 tha = *(const f32x4*)(th + tsrc*BB + m0 + lq*4);
    f32x4 thb = tha;
    if (tsrc > 0) thb = *(const f32x4*)(th + (tsrc-1)*BB + m0 + lq*4);

    f32x4 accR[4], accZ[4], accNH[4], accNI[4];
    #pragma unroll
    for (int t = 0; t < 4; ++t) { accR[t] = splat4(0.f); accZ[t] = splat4(0.f); accNH[t] = splat4(0.f); accNI[t] = splat4(0.f); }

    // h-part: hi & lo planes; r tiles 0,1 from WRT (LDS), r tiles 2,3 + z,n from regs;
    // fp8 n-residual B from global (L2). Per-accumulator op order == R2.
    #pragma unroll
    for (int kc = 0; kc < 8; ++kc) {
      const int ko = (kc*64 + lq*16) ^ swz;
      h8 ahi = *(const h8*)(HB + lr*1024 + ko);
      h8 alo = *(const h8*)(HB + lr*1024 + 512 + ko);
      h8 wr0 = *(const h8*)(WRT + wrt0 + ko);
      h8 wr1 = *(const h8*)(WRT + wrt0 + 8192 + ko);
      accR[0] = MFMA16(ahi, wr0, accR[0]);        accR[0] = MFMA16(alo, wr0, accR[0]);
      accR[1] = MFMA16(ahi, wr1, accR[1]);        accR[1] = MFMA16(alo, wr1, accR[1]);
      accR[2] = MFMA16(ahi, Wfr[0][kc], accR[2]); accR[2] = MFMA16(alo, Wfr[0][kc], accR[2]);
      accR[3] = MFMA16(ahi, Wfr[1][kc], accR[3]); accR[3] = MFMA16(alo, Wfr[1][kc], accR[3]);
      #pragma unroll
      for (int t = 0; t < 4; ++t) {
        accZ[t]  = MFMA16(ahi, Wfz[t][kc], accZ[t]);  accZ[t]  = MFMA16(alo, Wfz[t][kc], accZ[t]);
        accNH[t] = MFMA16(ahi, Wfn[t][kc], accNH[t]); accNH[t] = MFMA16(alo, Wfn[t][kc], accNH[t]);
      }
      long long a8 = pack_e4m3_h8(ahi);
      #pragma unroll
      for (int t = 0; t < 4; ++t) {
        int n = wave*64 + t*16 + lr;
        long long b8 = *(const long long*)(wlng + n*256 + kc*32 + lq*8);
        accNH[t] = MFMA8(a8, b8, accNH[t]);
      }
    }

    // x-part: R2 verbatim (WIH/WIL from LDS)
    h8 xhi, xlo;
    #pragma unroll
    for (int j = 0; j < 8; ++j) {
      float v = (j < 4) ? xa[j] : xb[j-4];
      f16 h = (f16)v;
      xhi[j] = h; xlo[j] = (f16)(v - (float)h);
    }
    long long ax8 = pack_e4m3_f32x8(xa, xb);
    #pragma unroll
    for (int t = 0; t < 4; ++t) {
      int nr = 0*256 + wave*64 + t*16 + lr;
      int nz = 256 + wave*64 + t*16 + lr;
      int nn = 512 + wave*64 + t*16 + lr;
      h8 br_ = *(const h8*)(WIH + nr*64 + ((lq*16) ^ ((lr & 3) << 4)));
      h8 bz_ = *(const h8*)(WIH + nz*64 + ((lq*16) ^ ((lr & 3) << 4)));
      h8 bn_ = *(const h8*)(WIH + nn*64 + ((lq*16) ^ ((lr & 3) << 4)));
      accR[t]  = MFMA16(xhi, br_, accR[t]);  accR[t]  = MFMA16(xlo, br_, accR[t]);
      accZ[t]  = MFMA16(xhi, bz_, accZ[t]);  accZ[t]  = MFMA16(xlo, bz_, accZ[t]);
      accNI[t] = MFMA16(xhi, bn_, accNI[t]); accNI[t] = MFMA16(xlo, bn_, accNI[t]);
      long long br8 = *(const long long*)(WIL + nr*32 + ((lq*8) ^ ((lr & 3) << 3)));
      long long bz8 = *(const long long*)(WIL + nz*32 + ((lq*8) ^ ((lr & 3) << 3)));
      long long bn8 = *(const long long*)(WIL + nn*32 + ((lq*8) ^ ((lr & 3) << 3)));
      accR[t]  = MFMA8(ax8, br8, accR[t]);
      accZ[t]  = MFMA8(ax8, bz8, accZ[t]);
      accNI[t] = MFMA8(ax8, bn8, accNI[t]);
    }

    __syncthreads();  // all reads of HB complete before in-place h' write

    // gate math (f32) + h' write (hi/lo) — R2 verbatim
    float dtv[4];
    #pragma unroll
    for (int r = 0; r < 4; ++r) dtv[r] = tha[r] - thb[r];
    #pragma unroll
    for (int t = 0; t < 4; ++t) {
      int c = wave*64 + t*16 + lr;
      const float* cc = CST + c*7;
      float w32r = cc[0], w32z = cc[1], w32n = cc[2];
      float br = cc[3], bz = cc[4], bin = cc[5], bhn = cc[6];
      #pragma unroll
      for (int r = 0; r < 4; ++r) {
        float rv = accR[t][r]*S + br + dtv[r]*w32r;
        float zv = accZ[t][r]*S + bz + dtv[r]*w32z;
        float iv = accNI[t][r]*S + bin + dtv[r]*w32n;
        float hn = accNH[t][r]*S + bhn;
        float rg = fsigm(rv), zg = fsigm(zv);
        float nv = ftanh(iv + rg*hn);
        float hv = nv + zg*(hreg[t][r] - nv);
        hreg[t][r] = hv;
        int row = lq*4 + r;
        f16 hh = (f16)hv;
        *(f16*)(HB + row*1024 + ((2*c) ^ ((row & 7) << 4))) = hh;
        *(f16*)(HB + row*1024 + 512 + ((2*c) ^ ((row & 7) << 4))) = (f16)(hv - (float)hh);
      }
    }
    __syncthreads();
  }

  // ---- z0 = (hT @ Wlat + blat)[:, :32] (hi+lo planes), redundant per wave ----
  f32x4 z0a = splat4(blat[lr]);
  f32x4 z0b = splat4(blat[16 + lr]);
  #pragma unroll
  for (int kc = 0; kc < 8; ++kc) {
    h8 ahi = *(const h8*)(HB + lr*1024 + ((kc*64 + lq*16) ^ swz));
    h8 alo = *(const h8*)(HB + lr*1024 + 512 + ((kc*64 + lq*16) ^ swz));
    h8 ba = *(const h8*)(ws + WS_WLAT + lr*512 + kc*64 + lq*16);
    h8 bb = *(const h8*)(ws + WS_WLAT + (16 + lr)*512 + kc*64 + lq*16);
    z0a = MFMA16(ahi, ba, z0a); z0a = MFMA16(alo, ba, z0a);
    z0b = MFMA16(ahi, bb, z0b); z0b = MFMA16(alo, bb, z0b);
  }

  // ---- tail buffers reuse the WIH region (R2 layout/offsets) ----
  char* TZ  = smem + 16384;   // [16][64B],  swz ^((row&3)<<4)
  char* TU1 = smem + 18432;   // [16][1024B], swz ^((row&7)<<4)
  char* TU2 = smem + 34816;   // [16][1024B]
  char* TD  = smem + 51200;   // [16][512B]

  auto Ffun = [&](f32x4 zina, f32x4 zinb, f32x4& ka, f32x4& kb) {
    if (wave == 0) {
      #pragma unroll
      for (int r = 0; r < 4; ++r) {
        int row = lq*4 + r;
        *(f16*)(TZ + row*64 + ((2*lr) ^ ((row & 3) << 4))) = (f16)zina[r];
        *(f16*)(TZ + row*64 + ((2*(16 + lr)) ^ ((row & 3) << 4))) = (f16)zinb[r];
      }
    }
    __syncthreads();
    h8 za = *(const h8*)(TZ + lr*64 + ((lq*16) ^ ((lr & 3) << 4)));
    #pragma unroll
    for (int st = 0; st < 8; ++st) {
      int n = wave*128 + st*16 + lr;
      f32x4 t0 = splat4(b1[n]);
      t0 = MFMA16(za, *(const h8*)(ws + WS_W1T + n*64 + lq*16), t0);
      #pragma unroll
      for (int r = 0; r < 4; ++r) {
        int row = lq*4 + r;
        *(f16*)(TU1 + row*1024 + ((2*n) ^ ((row & 7) << 4))) = (f16)ftanh(t0[r]);
      }
    }
    __syncthreads();
    #pragma unroll
    for (int st = 0; st < 8; ++st) {
      int n = wave*128 + st*16 + lr;
      f32x4 t0 = splat4(b2[n]);
      #pragma unroll
      for (int kc = 0; kc < 16; ++kc) {
        h8 a = *(const h8*)(TU1 + lr*1024 + ((kc*64 + lq*16) ^ ((lr & 7) << 4)));
        t0 = MFMA16(a, *(const h8*)(ws + WS_W2T + n*1024 + kc*64 + lq*16), t0);
      }
      #pragma unroll
      for (int r = 0; r < 4; ++r) {
        int row = lq*4 + r;
        *(f16*)(TU2 + row*1024 + ((2*n) ^ ((row & 7) << 4))) = (f16)ftanh(t0[r]);
      }
    }
    __syncthreads();
    f32x4 t0 = splat4(b3[lr]), t1 = splat4(b3[16 + lr]);
    #pragma unroll
    for (int kc = 0; kc < 16; ++kc) {
      h8 a = *(const h8*)(TU2 + lr*1024 + ((kc*64 + lq*16) ^ ((lr & 7) << 4)));
      t0 = MFMA16(a, *(const h8*)(ws + WS_W3T + lr*1024 + kc*64 + lq*16), t0);
      t1 = MFMA16(a, *(const h8*)(ws + WS_W3T + (16 + lr)*1024 + kc*64 + lq*16), t1);
    }
    ka = t0; kb = t1;
    __syncthreads();
  };

  f32x4 k1a, k1b, k2a, k2b, k3a, k3b, k4a, k4b;
  Ffun(z0a, z0b, k1a, k1b);
  Ffun(z0a + k1a*(1.f/3.f), z0b + k1b*(1.f/3.f), k2a, k2b);
  Ffun(z0a + k2a - k1a*(1.f/3.f), z0b + k2b - k1b*(1.f/3.f), k3a, k3b);
  Ffun(z0a + k1a - k2a + k3a, z0b + k1b - k2b + k3b, k4a, k4b);
  f32x4 zTa = z0a + (k1a + 3.f*k2a + 3.f*k3a + k4a)*0.125f;
  f32x4 zTb = z0b + (k1b + 3.f*k2b + 3.f*k3b + k4b)*0.125f;

  // ---- decoder (R2 verbatim) ----
  if (wave == 0) {
    #pragma unroll
    for (int r = 0; r < 4; ++r) {
      int row = lq*4 + r;
      *(f16*)(TZ + row*64 + ((2*lr) ^ ((row & 3) << 4))) = (f16)zTa[r];
      *(f16*)(TZ + row*64 + ((2*(16 + lr)) ^ ((row & 3) << 4))) = (f16)zTb[r];
    }
  }
  __syncthreads();
  {
    h8 za = *(const h8*)(TZ + lr*64 + ((lq*16) ^ ((lr & 3) << 4)));
    #pragma unroll
    for (int st = 0; st < 4; ++st) {
      int n = wave*64 + st*16 + lr;
      f32x4 t0 = splat4(bd1[n]);
      t0 = MFMA16(za, *(const h8*)(ws + WS_WD1T + n*64 + lq*16), t0);
      #pragma unroll
      for (int r = 0; r < 4; ++r) {
        int row = lq*4 + r;
        float v = t0[r] > 0.f ? t0[r] : 0.f;
        *(f16*)(TD + row*512 + ((2*n) ^ ((row & 7) << 4))) = (f16)v;
      }
    }
  }
  __syncthreads();
  if (wave == 0) {
    f32x4 o = splat4(0.f);
    #pragma unroll
    for (int kc = 0; kc < 8; ++kc) {
      h8 a = *(const h8*)(TD + lr*512 + ((kc*64 + lq*16) ^ ((lr & 7) << 4)));
      o = MFMA16(a, *(const h8*)(ws + WS_WD2T + lr*512 + kc*64 + lq*16), o);
    }
    if (lr < OUTD) {
      float q = bd2[lr];
      #pragma unroll
      for (int r = 0; r < 4; ++r) out[(m0 + lq*4 + r)*OUTD + lr] = o[r] + q;
    }
  }
}

extern "C" void kernel_launch(void* const* d_in, const int* in_sizes, int n_in,
                              void* d_out, int out_size, void* d_ws, size_t ws_size,
                              hipStream_t stream) {
  const float* x    = (const float*)d_in[0];
  const float* th   = (const float*)d_in[1];
  const float* Wih  = (const float*)d_in[2];
  const float* Whh  = (const float*)d_in[3];
  const float* bih  = (const float*)d_in[4];
  const float* bhh  = (const float*)d_in[5];
  const float* Wlat = (const float*)d_in[6];
  const float* blat = (const float*)d_in[7];
  const float* W1   = (const float*)d_in[8];
  const float* b1   = (const float*)d_in[9];
  const float* W2   = (const float*)d_in[10];
  const float* b2   = (const float*)d_in[11];
  const float* W3   = (const float*)d_in[12];
  const float* b3   = (const float*)d_in[13];
  const float* Wd1  = (const float*)d_in[14];
  const float* bd1  = (const float*)d_in[15];
  const float* Wd2  = (const float*)d_in[16];
  const float* bd2  = (const float*)d_in[17];
  (void)in_sizes; (void)n_in; (void)out_size; (void)ws_size;

  static int lds_set = 0;
  if (!lds_set) {
    hipFuncSetAttribute((const void*)gru_ode_kernel,
                        hipFuncAttributeMaxDynamicSharedMemorySize, LDS_SIZE);
    lds_set = 1;
  }

  prep_kernel<<<512, 512, 0, stream>>>(Wih, Whh, Wlat, W1, W2, W3, Wd1, Wd2, (char*)d_ws);
  gru_ode_kernel<<<256, 256, LDS_SIZE, stream>>>(x, th, Wih, bih, bhh, blat, b1, b2, b3,
                                                 bd1, bd2, (const char*)d_ws, (float*)d_out);
}

// Round 8
// 2560.989 us; speedup vs baseline: 1.3357x; 1.3357x over previous
//
#include <hip/hip_runtime.h>

typedef _Float16 f16;
typedef _Float16 h8 __attribute__((ext_vector_type(8)));
typedef float f32x4 __attribute__((ext_vector_type(4)));

#define MFMA16(a,b,c) __builtin_amdgcn_mfma_f32_16x16x32_f16((a),(b),(c),0,0,0)
#define MFMA8(a,b,c)  __builtin_amdgcn_mfma_f32_16x16x32_fp8_bf8((long)(a),(long)(b),(c),0,0,0)

#define TT 256
#define BB 4096
#define OUTD 8

// ---- workspace offsets (bytes), identical to round 2 ----
#define WS_WHH    0u         // [768][256] f16 * 2^8   (gate order r,z,n)
#define WS_WIHHI  393216u    // [768][32]  f16 * 2^8   (L2-streamed)
#define WS_WIHLO  442368u    // [768][32]  e5m2 residual * 2^8 (L2-streamed)
#define WS_WLON   466944u    // [256][256] e5m2 n-gate Whh residual * 2^8 (L2-streamed)
#define WS_WLAT   532480u    // [32][256]  f16
#define WS_W1T    548864u    // [512][32]  f16
#define WS_W2T    581632u    // [512][512] f16
#define WS_W3T    1105920u   // [32][512]  f16
#define WS_WD1T   1138688u   // [256][32]  f16
#define WS_WD2T   1155072u   // [16][256]  f16 (rows>=8 zero)

// ---- LDS offsets (bytes) ----
#define L_HB     0           // [16][1024]: hi [0,512) | lo [512,1024), swz ^((row&7)<<4)
#define L_WRT    16384       // FULL r-gate: [256 rows(=col)][512B] f16, swz ^((row&7)<<4)
#define L_CST    147456      // [256][7] f32
#define LDS_SIZE 155648

__device__ __forceinline__ float fsigm(float x) {
  return __builtin_amdgcn_rcpf(1.f + __builtin_amdgcn_exp2f(-1.44269504f * x));
}
__device__ __forceinline__ float ftanh(float x) {
  return 1.f - 2.f * __builtin_amdgcn_rcpf(1.f + __builtin_amdgcn_exp2f(2.88539008f * x));
}
__device__ __forceinline__ f32x4 splat4(float v) { f32x4 r = {v, v, v, v}; return r; }

__device__ __forceinline__ long long pack_e4m3_h8(h8 a) {
  int lo = __builtin_amdgcn_cvt_pk_fp8_f32((float)a[0], (float)a[1], 0, false);
  lo = __builtin_amdgcn_cvt_pk_fp8_f32((float)a[2], (float)a[3], lo, true);
  int hi = __builtin_amdgcn_cvt_pk_fp8_f32((float)a[4], (float)a[5], 0, false);
  hi = __builtin_amdgcn_cvt_pk_fp8_f32((float)a[6], (float)a[7], hi, true);
  return (long long)(unsigned)lo | ((long long)hi << 32);
}
__device__ __forceinline__ long long pack_e4m3_f32x8(f32x4 a, f32x4 b) {
  int lo = __builtin_amdgcn_cvt_pk_fp8_f32(a[0], a[1], 0, false);
  lo = __builtin_amdgcn_cvt_pk_fp8_f32(a[2], a[3], lo, true);
  int hi = __builtin_amdgcn_cvt_pk_fp8_f32(b[0], b[1], 0, false);
  hi = __builtin_amdgcn_cvt_pk_fp8_f32(b[2], b[3], hi, true);
  return (long long)(unsigned)lo | ((long long)hi << 32);
}

// ---------------- prep: unchanged from round 2 (validated) ----------------
__global__ __launch_bounds__(512) void prep_kernel(
    const float* __restrict__ Wih, const float* __restrict__ Whh,
    const float* __restrict__ Wlat, const float* __restrict__ W1,
    const float* __restrict__ W2, const float* __restrict__ W3,
    const float* __restrict__ Wd1, const float* __restrict__ Wd2,
    char* __restrict__ ws) {
  int idx = blockIdx.x * 512 + threadIdx.x;
  if (idx < 768*256) {
    int n = idx >> 8, k = idx & 255;
    ((f16*)(ws + WS_WHH))[n*256 + k] = (f16)(Whh[k*768 + n] * 256.f);
  }
  if (idx < 768*32) {
    int n = idx >> 5, k = idx & 31;
    ((f16*)(ws + WS_WIHHI))[n*32 + k] = (f16)(Wih[k*768 + n] * 256.f);
  }
  if (idx < 768*16) {
    int n = idx >> 4, k2 = (idx & 15) * 2;
    float w0 = Wih[k2*768 + n] * 256.f;
    float w1 = Wih[(k2+1)*768 + n] * 256.f;
    float r0 = w0 - (float)(f16)w0;
    float r1 = w1 - (float)(f16)w1;
    int p = __builtin_amdgcn_cvt_pk_bf8_f32(r0, r1, 0, false);
    *(short*)(ws + WS_WIHLO + n*32 + k2) = (short)p;
  }
  if (idx < 256*128) {
    int n = idx >> 7, k2 = (idx & 127) * 2;
    int c = 512 + n;
    float w0 = Whh[k2*768 + c] * 256.f;
    float w1 = Whh[(k2+1)*768 + c] * 256.f;
    float r0 = w0 - (float)(f16)w0;
    float r1 = w1 - (float)(f16)w1;
    int p = __builtin_amdgcn_cvt_pk_bf8_f32(r0, r1, 0, false);
    *(short*)(ws + WS_WLON + n*256 + k2) = (short)p;
  }
  if (idx < 32*256)  { int n = idx >> 8, k = idx & 255; ((f16*)(ws + WS_WLAT))[n*256 + k] = (f16)Wlat[k*64 + n]; }
  if (idx < 512*32)  { int n = idx >> 5, k = idx & 31;  ((f16*)(ws + WS_W1T))[n*32 + k]   = (f16)W1[k*512 + n]; }
  if (idx < 512*512) { int n = idx >> 9, k = idx & 511; ((f16*)(ws + WS_W2T))[n*512 + k]  = (f16)W2[k*512 + n]; }
  if (idx < 32*512)  { int n = idx >> 9, k = idx & 511; ((f16*)(ws + WS_W3T))[n*512 + k]  = (f16)W3[k*32 + n]; }
  if (idx < 256*32)  { int n = idx >> 5, k = idx & 31;  ((f16*)(ws + WS_WD1T))[n*32 + k]  = (f16)Wd1[k*256 + n]; }
  if (idx < 16*256)  { int n = idx >> 8, k = idx & 255; ((f16*)(ws + WS_WD2T))[n*256 + k] = (n < 8) ? (f16)Wd2[k*8 + n] : (f16)0.f; }
}

// ---------------- main: 256 blocks x 512 threads (8 waves, 2/SIMD), 16 rows/block ----------------
// Geometry that fits: per wave 32 cols/gate. Register-resident: z,n gates (32 h8 =
// 128 VGPR, under the 256 cap -> no sink/spill). Full r-gate in LDS (128 KB).
// WIH-hi / WIH-res / WLN-res streamed from L2 (linear addrs, value-identical, cf R5/R7).
__global__ __launch_bounds__(512) void gru_ode_kernel(
    const float* __restrict__ xh, const float* __restrict__ th,
    const float* __restrict__ Wih_f, const float* __restrict__ bih,
    const float* __restrict__ bhh, const float* __restrict__ blat,
    const float* __restrict__ b1, const float* __restrict__ b2,
    const float* __restrict__ b3, const float* __restrict__ bd1,
    const float* __restrict__ bd2, const char* __restrict__ ws,
    float* __restrict__ out) {
  extern __shared__ char smem[];
  char* HB  = smem + L_HB;
  char* WRT = smem + L_WRT;
  float* CST = (float*)(smem + L_CST);
  const char* wlng = ws + WS_WLON;
  const char* wilg = ws + WS_WIHLO;
  const char* wihg = ws + WS_WIHHI;

  const int tid  = threadIdx.x;
  const int wave = tid >> 6;
  const int lane = tid & 63;
  const int lq   = lane >> 4;
  const int lr   = lane & 15;
  const int m0   = blockIdx.x << 4;
  const int swz  = (lr & 7) << 4;
  const int lq16 = lq * 16, lq8 = lq * 8;
  const float S  = 1.f / 256.f;

  // ---- stage LDS ----
  #pragma unroll
  for (int it = 0; it < 8; ++it) ((unsigned*)HB)[tid + it*512] = 0u;
  {
    // full r-gate: col c (= Whh row c, gate r first) -> LDS row c, [c][512B]
    #pragma unroll
    for (int it = 0; it < 64; ++it) {
      int i = tid + it*512;             // dword index, 32768 total
      int row = i >> 7, kw = i & 127;
      unsigned v = *(const unsigned*)(ws + WS_WHH + row*512 + kw*4);
      *(unsigned*)(WRT + row*512 + ((kw*4) ^ ((row & 7) << 4))) = v;
    }
  }
  if (tid < 256) {
    int c = tid;
    CST[c*7 + 0] = Wih_f[32*768 + c];
    CST[c*7 + 1] = Wih_f[32*768 + 256 + c];
    CST[c*7 + 2] = Wih_f[32*768 + 512 + c];
    CST[c*7 + 3] = bih[c] + bhh[c];
    CST[c*7 + 4] = bih[256 + c] + bhh[256 + c];
    CST[c*7 + 5] = bih[512 + c];
    CST[c*7 + 6] = bhh[512 + c];
  }

  // ---- resident weights: z,n gates, 2 tiles each = 32 h8 (128 VGPR) ----
  h8 Wfz[2][8], Wfn[2][8];
  #pragma unroll
  for (int t = 0; t < 2; ++t) {
    const char* bz = ws + WS_WHH + (256 + wave*32 + t*16 + lr)*512 + lq16;
    const char* bn = ws + WS_WHH + (512 + wave*32 + t*16 + lr)*512 + lq16;
    #pragma unroll
    for (int kc = 0; kc < 8; ++kc) {
      Wfz[t][kc] = *(const h8*)(bz + kc*64);
      Wfn[t][kc] = *(const h8*)(bn + kc*64);
    }
  }

  float hreg[2][4];
  #pragma unroll
  for (int t = 0; t < 2; ++t)
    #pragma unroll
    for (int r = 0; r < 4; ++r) hreg[t][r] = 0.f;

  const int wrt0 = (wave*32 + lr)*512;   // r tile0 row; tile1 at +8192
  const int wln0 = (wave*32 + lr)*256;   // wln tile0 row; tile1 at +4096

  __syncthreads();

  // ---- GRU loop (reversed sequence): in-place HB, 2 barriers/step (R2 protocol) ----
  #pragma unroll 1
  for (int s = 0; s < 256; ++s) {
    const int tsrc = 255 - s;
    f32x4 xa = *(const f32x4*)(xh + (size_t)(tsrc*BB + m0 + lr)*32 + lq8);
    f32x4 xb = *(const f32x4*)(xh + (size_t)(tsrc*BB + m0 + lr)*32 + lq8 + 4);
    f32x4 tha = *(const f32x4*)(th + tsrc*BB + m0 + lq*4);
    f32x4 thb = tha;
    if (tsrc > 0) thb = *(const f32x4*)(th + (tsrc-1)*BB + m0 + lq*4);

    f32x4 accR[2], accZ[2], accNH[2], accNI[2];
    #pragma unroll
    for (int t = 0; t < 2; ++t) { accR[t] = splat4(0.f); accZ[t] = splat4(0.f); accNH[t] = splat4(0.f); accNI[t] = splat4(0.f); }

    // h-part: hi & lo planes; r from LDS (WRT), z,n from regs; fp8 n-residual from L2.
    // Per-accumulator op order == R2: (hi, lo) per kc, fp8 after, per kc.
    #pragma unroll
    for (int kc = 0; kc < 8; ++kc) {
      const int ko = (kc*64 + lq16) ^ swz;
      h8 ahi = *(const h8*)(HB + lr*1024 + ko);
      h8 alo = *(const h8*)(HB + lr*1024 + 512 + ko);
      h8 wr0 = *(const h8*)(WRT + wrt0 + ko);
      h8 wr1 = *(const h8*)(WRT + wrt0 + 8192 + ko);
      accR[0] = MFMA16(ahi, wr0, accR[0]);       accR[0] = MFMA16(alo, wr0, accR[0]);
      accR[1] = MFMA16(ahi, wr1, accR[1]);       accR[1] = MFMA16(alo, wr1, accR[1]);
      accZ[0] = MFMA16(ahi, Wfz[0][kc], accZ[0]); accZ[0] = MFMA16(alo, Wfz[0][kc], accZ[0]);
      accZ[1] = MFMA16(ahi, Wfz[1][kc], accZ[1]); accZ[1] = MFMA16(alo, Wfz[1][kc], accZ[1]);
      accNH[0] = MFMA16(ahi, Wfn[0][kc], accNH[0]); accNH[0] = MFMA16(alo, Wfn[0][kc], accNH[0]);
      accNH[1] = MFMA16(ahi, Wfn[1][kc], accNH[1]); accNH[1] = MFMA16(alo, Wfn[1][kc], accNH[1]);
      long long a8 = pack_e4m3_h8(ahi);
      long long b80 = *(const long long*)(wlng + wln0 + kc*32 + lq8);
      long long b81 = *(const long long*)(wlng + wln0 + 4096 + kc*32 + lq8);
      accNH[0] = MFMA8(a8, b80, accNH[0]);
      accNH[1] = MFMA8(a8, b81, accNH[1]);
    }

    // x-part: exact f32 -> f16 hi/lo + fp8 residual; WIH-hi + WIL from L2 (linear)
    h8 xhi, xlo;
    #pragma unroll
    for (int j = 0; j < 8; ++j) {
      float v = (j < 4) ? xa[j] : xb[j-4];
      f16 h = (f16)v;
      xhi[j] = h; xlo[j] = (f16)(v - (float)h);
    }
    long long ax8 = pack_e4m3_f32x8(xa, xb);
    #pragma unroll
    for (int t = 0; t < 2; ++t) {
      int nr =       wave*32 + t*16 + lr;
      int nz = 256 + wave*32 + t*16 + lr;
      int nn = 512 + wave*32 + t*16 + lr;
      h8 br_ = *(const h8*)(wihg + nr*64 + lq16);
      h8 bz_ = *(const h8*)(wihg + nz*64 + lq16);
      h8 bn_ = *(const h8*)(wihg + nn*64 + lq16);
      accR[t]  = MFMA16(xhi, br_, accR[t]);  accR[t]  = MFMA16(xlo, br_, accR[t]);
      accZ[t]  = MFMA16(xhi, bz_, accZ[t]);  accZ[t]  = MFMA16(xlo, bz_, accZ[t]);
      accNI[t] = MFMA16(xhi, bn_, accNI[t]); accNI[t] = MFMA16(xlo, bn_, accNI[t]);
      long long br8 = *(const long long*)(wilg + nr*32 + lq8);
      long long bz8 = *(const long long*)(wilg + nz*32 + lq8);
      long long bn8 = *(const long long*)(wilg + nn*32 + lq8);
      accR[t]  = MFMA8(ax8, br8, accR[t]);
      accZ[t]  = MFMA8(ax8, bz8, accZ[t]);
      accNI[t] = MFMA8(ax8, bn8, accNI[t]);
    }

    __syncthreads();  // all reads of HB complete before in-place h' write

    float dtv[4];
    #pragma unroll
    for (int r = 0; r < 4; ++r) dtv[r] = tha[r] - thb[r];
    #pragma unroll
    for (int t = 0; t < 2; ++t) {
      int c = wave*32 + t*16 + lr;
      const float* cc = CST + c*7;
      float w32r = cc[0], w32z = cc[1], w32n = cc[2];
      float br = cc[3], bz = cc[4], bin = cc[5], bhn = cc[6];
      #pragma unroll
      for (int r = 0; r < 4; ++r) {
        float rv = accR[t][r]*S + br + dtv[r]*w32r;
        float zv = accZ[t][r]*S + bz + dtv[r]*w32z;
        float iv = accNI[t][r]*S + bin + dtv[r]*w32n;
        float hn = accNH[t][r]*S + bhn;
        float rg = fsigm(rv), zg = fsigm(zv);
        float nv = ftanh(iv + rg*hn);
        float hv = nv + zg*(hreg[t][r] - nv);
        hreg[t][r] = hv;
        int row = lq*4 + r;
        f16 hh = (f16)hv;
        *(f16*)(HB + row*1024 + ((2*c) ^ ((row & 7) << 4))) = hh;
        *(f16*)(HB + row*1024 + 512 + ((2*c) ^ ((row & 7) << 4))) = (f16)(hv - (float)hh);
      }
    }
    __syncthreads();
  }

  // ---- z0 = (hT @ Wlat + blat)[:, :32] (hi+lo planes), redundant per wave ----
  f32x4 z0a = splat4(blat[lr]);
  f32x4 z0b = splat4(blat[16 + lr]);
  #pragma unroll
  for (int kc = 0; kc < 8; ++kc) {
    h8 ahi = *(const h8*)(HB + lr*1024 + ((kc*64 + lq16) ^ swz));
    h8 alo = *(const h8*)(HB + lr*1024 + 512 + ((kc*64 + lq16) ^ swz));
    h8 ba = *(const h8*)(ws + WS_WLAT + lr*512 + kc*64 + lq16);
    h8 bb = *(const h8*)(ws + WS_WLAT + (16 + lr)*512 + kc*64 + lq16);
    z0a = MFMA16(ahi, ba, z0a); z0a = MFMA16(alo, ba, z0a);
    z0b = MFMA16(ahi, bb, z0b); z0b = MFMA16(alo, bb, z0b);
  }

  // ---- tail buffers reuse the WRT region (dead after loop) ----
  char* TZ  = smem + L_WRT;            // [16][64B],  swz ^((row&3)<<4)
  char* TU1 = smem + L_WRT + 2048;     // [16][1024B], swz ^((row&7)<<4)
  char* TU2 = smem + L_WRT + 18432;    // [16][1024B]
  char* TD  = smem + L_WRT + 34816;    // [16][512B]

  auto Ffun = [&](f32x4 zina, f32x4 zinb, f32x4& ka, f32x4& kb) {
    if (wave == 0) {
      #pragma unroll
      for (int r = 0; r < 4; ++r) {
        int row = lq*4 + r;
        *(f16*)(TZ + row*64 + ((2*lr) ^ ((row & 3) << 4))) = (f16)zina[r];
        *(f16*)(TZ + row*64 + ((2*(16 + lr)) ^ ((row & 3) << 4))) = (f16)zinb[r];
      }
    }
    __syncthreads();
    h8 za = *(const h8*)(TZ + lr*64 + ((lq16) ^ ((lr & 3) << 4)));
    #pragma unroll
    for (int st = 0; st < 4; ++st) {
      int n = wave*64 + st*16 + lr;
      f32x4 t0 = splat4(b1[n]);
      t0 = MFMA16(za, *(const h8*)(ws + WS_W1T + n*64 + lq16), t0);
      #pragma unroll
      for (int r = 0; r < 4; ++r) {
        int row = lq*4 + r;
        *(f16*)(TU1 + row*1024 + ((2*n) ^ ((row & 7) << 4))) = (f16)ftanh(t0[r]);
      }
    }
    __syncthreads();
    #pragma unroll
    for (int st = 0; st < 4; ++st) {
      int n = wave*64 + st*16 + lr;
      f32x4 t0 = splat4(b2[n]);
      #pragma unroll
      for (int kc = 0; kc < 16; ++kc) {
        h8 a = *(const h8*)(TU1 + lr*1024 + ((kc*64 + lq16) ^ ((lr & 7) << 4)));
        t0 = MFMA16(a, *(const h8*)(ws + WS_W2T + n*1024 + kc*64 + lq16), t0);
      }
      #pragma unroll
      for (int r = 0; r < 4; ++r) {
        int row = lq*4 + r;
        *(f16*)(TU2 + row*1024 + ((2*n) ^ ((row & 7) << 4))) = (f16)ftanh(t0[r]);
      }
    }
    __syncthreads();
    f32x4 t0 = splat4(b3[lr]), t1 = splat4(b3[16 + lr]);
    #pragma unroll
    for (int kc = 0; kc < 16; ++kc) {
      h8 a = *(const h8*)(TU2 + lr*1024 + ((kc*64 + lq16) ^ ((lr & 7) << 4)));
      t0 = MFMA16(a, *(const h8*)(ws + WS_W3T + lr*1024 + kc*64 + lq16), t0);
      t1 = MFMA16(a, *(const h8*)(ws + WS_W3T + (16 + lr)*1024 + kc*64 + lq16), t1);
    }
    ka = t0; kb = t1;
    __syncthreads();
  };

  f32x4 k1a, k1b, k2a, k2b, k3a, k3b, k4a, k4b;
  Ffun(z0a, z0b, k1a, k1b);
  Ffun(z0a + k1a*(1.f/3.f), z0b + k1b*(1.f/3.f), k2a, k2b);
  Ffun(z0a + k2a - k1a*(1.f/3.f), z0b + k2b - k1b*(1.f/3.f), k3a, k3b);
  Ffun(z0a + k1a - k2a + k3a, z0b + k1b - k2b + k3b, k4a, k4b);
  f32x4 zTa = z0a + (k1a + 3.f*k2a + 3.f*k3a + k4a)*0.125f;
  f32x4 zTb = z0b + (k1b + 3.f*k2b + 3.f*k3b + k4b)*0.125f;

  // ---- decoder ----
  if (wave == 0) {
    #pragma unroll
    for (int r = 0; r < 4; ++r) {
      int row = lq*4 + r;
      *(f16*)(TZ + row*64 + ((2*lr) ^ ((row & 3) << 4))) = (f16)zTa[r];
      *(f16*)(TZ + row*64 + ((2*(16 + lr)) ^ ((row & 3) << 4))) = (f16)zTb[r];
    }
  }
  __syncthreads();
  {
    h8 za = *(const h8*)(TZ + lr*64 + ((lq16) ^ ((lr & 3) << 4)));
    #pragma unroll
    for (int st = 0; st < 2; ++st) {
      int n = wave*32 + st*16 + lr;
      f32x4 t0 = splat4(bd1[n]);
      t0 = MFMA16(za, *(const h8*)(ws + WS_WD1T + n*64 + lq16), t0);
      #pragma unroll
      for (int r = 0; r < 4; ++r) {
        int row = lq*4 + r;
        float v = t0[r] > 0.f ? t0[r] : 0.f;
        *(f16*)(TD + row*512 + ((2*n) ^ ((row & 7) << 4))) = (f16)v;
      }
    }
  }
  __syncthreads();
  if (wave == 0) {
    f32x4 o = splat4(0.f);
    #pragma unroll
    for (int kc = 0; kc < 8; ++kc) {
      h8 a = *(const h8*)(TD + lr*512 + ((kc*64 + lq16) ^ ((lr & 7) << 4)));
      o = MFMA16(a, *(const h8*)(ws + WS_WD2T + lr*512 + kc*64 + lq16), o);
    }
    if (lr < OUTD) {
      float q = bd2[lr];
      #pragma unroll
      for (int r = 0; r < 4; ++r) out[(m0 + lq*4 + r)*OUTD + lr] = o[r] + q;
    }
  }
}

extern "C" void kernel_launch(void* const* d_in, const int* in_sizes, int n_in,
                              void* d_out, int out_size, void* d_ws, size_t ws_size,
                              hipStream_t stream) {
  const float* x    = (const float*)d_in[0];
  const float* th   = (const float*)d_in[1];
  const float* Wih  = (const float*)d_in[2];
  const float* Whh  = (const float*)d_in[3];
  const float* bih  = (const float*)d_in[4];
  const float* bhh  = (const float*)d_in[5];
  const float* Wlat = (const float*)d_in[6];
  const float* blat = (const float*)d_in[7];
  const float* W1   = (const float*)d_in[8];
  const float* b1   = (const float*)d_in[9];
  const float* W2   = (const float*)d_in[10];
  const float* b2   = (const float*)d_in[11];
  const float* W3   = (const float*)d_in[12];
  const float* b3   = (const float*)d_in[13];
  const float* Wd1  = (const float*)d_in[14];
  const float* bd1  = (const float*)d_in[15];
  const float* Wd2  = (const float*)d_in[16];
  const float* bd2  = (const float*)d_in[17];
  (void)in_sizes; (void)n_in; (void)out_size; (void)ws_size;

  static int lds_set = 0;
  if (!lds_set) {
    hipFuncSetAttribute((const void*)gru_ode_kernel,
                        hipFuncAttributeMaxDynamicSharedMemorySize, LDS_SIZE);
    lds_set = 1;
  }

  prep_kernel<<<512, 512, 0, stream>>>(Wih, Whh, Wlat, W1, W2, W3, Wd1, Wd2, (char*)d_ws);
  gru_ode_kernel<<<256, 512, LDS_SIZE, stream>>>(x, th, Wih, bih, bhh, blat, b1, b2, b3,
                                                 bd1, bd2, (const char*)d_ws, (float*)d_out);
}